// Round 3
// baseline (910.215 us; speedup 1.0000x reference)
//
#include <hip/hip_runtime.h>
#include <math.h>
#include <utility>

#define NLEADS 61
#define AIL __attribute__((always_inline))

// Guaranteed-unroll helper with forced inlining of the body lambda.
template <int... Is, typename F>
__device__ __forceinline__ void sf_(std::integer_sequence<int, Is...>, F&& f) {
    (f(std::integral_constant<int, Is>{}), ...);
}
template <int N, typename F>
__device__ __forceinline__ void static_for(F&& f) {
    sf_(std::make_integer_sequence<int, N>{}, (F&&)f);
}

__device__ __forceinline__ float4 ld4(const float* p) { return *(const float4*)p; }
__device__ __forceinline__ float2 ld2(const float* p) { return *(const float2*)p; }

template <int C> __device__ __forceinline__ float f4c(float4 v) {
    if constexpr (C == 0) return v.x;
    else if constexpr (C == 1) return v.y;
    else if constexpr (C == 2) return v.z;
    else return v.w;
}
template <int C> __device__ __forceinline__ float f6(float4 a, float2 b) {
    if constexpr (C < 4) return f4c<C>(a);
    else if constexpr (C == 4) return b.x;
    else return b.y;
}
template <int C> __device__ __forceinline__ float f8(float4 a, float4 b) {
    if constexpr (C < 4) return f4c<C>(a);
    else return f4c<C - 4>(b);
}
template <int K> __device__ __forceinline__ float w12(float4 w0, float4 w1, float4 w2) {
    if constexpr (K < 4) return f4c<K>(w0);
    else if constexpr (K < 8) return f4c<K - 4>(w1);
    else return f4c<K - 8>(w2);
}

// LDS layout (floats), total 13296 = 53.18 KB -> 3 blocks/CU.
//  sA   [0..9791]     : phase0-1: sxp[34][256] (+w1s@8704[96], b1s@8800[8])
//                       phase2  : h1p[8][18][68] (padded, zero border)
//                       phase3+ : sh3[256] @0, spart[256] @256, shf[64] @512, slog[3] @576
//  w2s  [9792..11327] : w2 (16*8*12)
//  sh2p [11328..13247]: h2p[16][6][20] padded;  reused as sfc[195] in phase4
//  sB   [13248..13295]: b2s[16] @0, b3s[32] @16
#define S_A   0
#define S_W1  8704
#define S_B1  8800
#define S_W2  9792
#define S_H2  11328
#define S_BB  13248
#define S_TOT 13296

__global__ __launch_bounds__(256, 3)
void lead_cnn_kernel(const float* __restrict__ x,
                     const float* __restrict__ w1g, const float* __restrict__ b1g,
                     const float* __restrict__ w2g, const float* __restrict__ b2g,
                     const float* __restrict__ w3g, const float* __restrict__ b3g,
                     const float* __restrict__ w4g, const float* __restrict__ b4g,
                     const float* __restrict__ fcwg, const float* __restrict__ fcbg,
                     float* __restrict__ preds)
{
    __shared__ __align__(16) float smem[S_TOT];
    float* const sA   = smem + S_A;
    float* const w1s  = smem + S_W1;
    float* const b1s  = smem + S_B1;
    float* const w2s  = smem + S_W2;
    float* const sh2p = smem + S_H2;
    float* const sB   = smem + S_BB;

    const int t = threadIdx.x;
    const int b = blockIdx.x;
    const int l = blockIdx.y;

    // ================= phase 0: stage x (padded 34x256, zero border) + weights ====
    {
        const float* xg = x + ((size_t)b * NLEADS + l) * 8000;
        for (int i = t; i < 8704; i += 256) {
            const int R = i >> 8, C = i & 255;
            const int r = R - 1, c = C - 2;
            const bool ok = ((unsigned)r < 32u) & ((unsigned)c < 250u);
            sA[i] = ok ? xg[r * 250 + c] : 0.f;
        }
        if (t < 96) w1s[t] = w1g[l * 96 + t];
        if (t < 8)  b1s[t] = b1g[l * 8 + t];
        for (int i = t; i < 1536; i += 256) w2s[i] = w2g[l * 1536 + i];
        if (t < 16) sB[t] = b2g[l * 16 + t];
        else if (t < 48) sB[t] = b3g[l * 32 + (t - 16)];
    }
    __syncthreads();

    // ===== conv1 (8,1,3,4) s(1,2) p(1,2) + pool2 + relu -> h1p (8,16,63) =========
    float acc1[32];   // [it*8+oc], constexpr-indexed only
    static_for<4>([&](auto IT) AIL {
        constexpr int it = IT.value;
        const int item = t + it * 256;        // 1008..1023: compute garbage, never stored
        const int ph = item / 63;
        const int pw = item - ph * 63;
        const float* bp = sA + (2 * ph) * 256 + 4 * pw;   // padded row 2ph, col 4pw (16B-aligned)
        float4 xa[4]; float2 xb[4];
        static_for<4>([&](auto R) AIL {
            constexpr int r = R.value;
            xa[r] = ld4(bp + r * 256);
            xb[r] = ld2(bp + r * 256 + 4);
        });
        static_for<8>([&](auto OC) AIL {
            constexpr int oc = OC.value;
            const float4 q0 = ld4(w1s + oc * 12);
            const float4 q1 = ld4(w1s + oc * 12 + 4);
            const float4 q2 = ld4(w1s + oc * 12 + 8);
            float p00 = 0.f, p01 = 0.f, p10 = 0.f, p11 = 0.f;
            static_for<3>([&](auto KH) AIL {
                constexpr int kh = KH.value;
                static_for<4>([&](auto KW) AIL {
                    constexpr int kw = KW.value;
                    const float wv = w12<kh * 4 + kw>(q0, q1, q2);
                    p00 = fmaf(wv, f6<kw>(xa[kh], xb[kh]), p00);
                    p01 = fmaf(wv, f6<kw + 2>(xa[kh], xb[kh]), p01);
                    p10 = fmaf(wv, f6<kw>(xa[kh + 1], xb[kh + 1]), p10);
                    p11 = fmaf(wv, f6<kw + 2>(xa[kh + 1], xb[kh + 1]), p11);
                });
            });
            const float m = fmaxf(fmaxf(p00, p01), fmaxf(p10, p11));
            acc1[it * 8 + oc] = fmaxf(m + b1s[oc], 0.f);
        });
    });
    __syncthreads();   // all sxp/w1s reads done; sA becomes h1p[8][18][68]

    static_for<4>([&](auto IT) AIL {
        constexpr int it = IT.value;
        const int item = t + it * 256;
        if (item < 1008) {
            const int ph = item / 63;
            const int pw = item - ph * 63;
            const int base = (ph + 1) * 68 + (pw + 1);
            static_for<8>([&](auto OC) AIL {
                constexpr int oc = OC.value;
                sA[oc * 1224 + base] = acc1[it * 8 + oc];
            });
        }
    });
    // zero h1p border (R=0, R=17, C=0, C=64), disjoint from interior
    for (int i = t; i < 1296; i += 256) {
        const int ch = i / 162;
        const int j = i - ch * 162;
        int R, C;
        if (j < 130) { R = (j < 65) ? 0 : 17; C = (j < 65) ? j : (j - 65); }
        else { const int j2 = j - 130; R = 1 + (j2 >> 1); C = (j2 & 1) ? 64 : 0; }
        sA[ch * 1224 + R * 68 + C] = 0.f;
    }
    __syncthreads();

    // ===== conv2 (16,8,4,3) s(2,2) p(1,1) + pool2 + relu -> h2p (16,4,16) ========
    {
        const int s2 = t & 63, og = t >> 6;   // og wave-uniform
        const int ph2 = s2 >> 4, pw2 = s2 & 15;
        float acc2[16];
        static_for<16>([&](auto I) AIL { acc2[I.value] = 0.f; });
        static_for<8>([&](auto IC) AIL {
            constexpr int ic = IC.value;
            const float* hp = sA + ic * 1224 + (4 * ph2) * 68 + 4 * pw2;  // 16B-aligned
            float4 ya[6], yb[6];
            static_for<6>([&](auto R) AIL {
                constexpr int r = R.value;
                ya[r] = ld4(hp + r * 68);
                yb[r] = ld4(hp + r * 68 + 4);
            });
            static_for<4>([&](auto OL) AIL {
                constexpr int ol = OL.value;
                const int oc = og * 4 + ol;
                const float* wp = w2s + oc * 96 + ic * 12;   // 16B-aligned, wave-uniform
                const float4 q0 = ld4(wp), q1 = ld4(wp + 4), q2 = ld4(wp + 8);
                static_for<4>([&](auto KH) AIL {
                    constexpr int kh = KH.value;
                    static_for<3>([&](auto KW) AIL {
                        constexpr int kw = KW.value;
                        const float wv = w12<kh * 3 + kw>(q0, q1, q2);
                        acc2[ol * 4 + 0] = fmaf(wv, f8<kw>(ya[kh], yb[kh]), acc2[ol * 4 + 0]);
                        acc2[ol * 4 + 1] = fmaf(wv, f8<kw + 2>(ya[kh], yb[kh]), acc2[ol * 4 + 1]);
                        acc2[ol * 4 + 2] = fmaf(wv, f8<kw>(ya[kh + 2], yb[kh + 2]), acc2[ol * 4 + 2]);
                        acc2[ol * 4 + 3] = fmaf(wv, f8<kw + 2>(ya[kh + 2], yb[kh + 2]), acc2[ol * 4 + 3]);
                    });
                });
            });
        });
        static_for<4>([&](auto OL) AIL {
            constexpr int ol = OL.value;
            const int oc = og * 4 + ol;
            const float m = fmaxf(fmaxf(acc2[ol * 4 + 0], acc2[ol * 4 + 1]),
                                  fmaxf(acc2[ol * 4 + 2], acc2[ol * 4 + 3]));
            sh2p[oc * 120 + (ph2 + 1) * 20 + (pw2 + 1)] = fmaxf(m + sB[oc], 0.f);
        });
        // zero h2p border
        for (int i = t; i < 896; i += 256) {
            const int ch = i / 56;
            const int j = i - ch * 56;
            int R, C;
            if (j < 40) { R = (j < 20) ? 0 : 5; C = (j < 20) ? j : (j - 20); }
            else { const int j2 = j - 40; R = 1 + (j2 >> 2); C = ((j2 & 3) == 0) ? 0 : (16 + (j2 & 3)); }
            sh2p[ch * 120 + R * 20 + C] = 0.f;
        }
    }
    __syncthreads();

    // ===== conv3 (32,16,3,4) s(1,2) p(1,1) + pool2 + relu -> h3p (32,2,4) ========
    {
        const int oc3 = t >> 3, s3 = t & 7;
        const int ph3 = s3 >> 2, pw3 = s3 & 3;
        float a30 = 0.f, a31 = 0.f, a32 = 0.f, a33 = 0.f;
        const float* w3l = w3g + (size_t)l * 6144 + oc3 * 192;
        static_for<16>([&](auto IC) AIL {
            constexpr int ic = IC.value;
            const float* zp = sh2p + ic * 120 + (2 * ph3) * 20 + 4 * pw3;  // 16B-aligned
            float4 za[4]; float2 zb[4];
            static_for<4>([&](auto R) AIL {
                constexpr int r = R.value;
                za[r] = ld4(zp + r * 20);
                zb[r] = ld2(zp + r * 20 + 4);
            });
            const float4 q0 = ld4(w3l + ic * 12);
            const float4 q1 = ld4(w3l + ic * 12 + 4);
            const float4 q2 = ld4(w3l + ic * 12 + 8);
            static_for<3>([&](auto KH) AIL {
                constexpr int kh = KH.value;
                static_for<4>([&](auto KW) AIL {
                    constexpr int kw = KW.value;
                    const float wv = w12<kh * 4 + kw>(q0, q1, q2);
                    a30 = fmaf(wv, f6<kw>(za[kh], zb[kh]), a30);
                    a31 = fmaf(wv, f6<kw + 2>(za[kh], zb[kh]), a31);
                    a32 = fmaf(wv, f6<kw>(za[kh + 1], zb[kh + 1]), a32);
                    a33 = fmaf(wv, f6<kw + 2>(za[kh + 1], zb[kh + 1]), a33);
                });
            });
        });
        const float m = fmaxf(fmaxf(a30, a31), fmaxf(a32, a33));
        sA[oc3 * 8 + s3] = fmaxf(m + sB[16 + oc3], 0.f);   // sh3 @ sA[0..255]
    }
    __syncthreads();

    // ===== conv4 (64,32,2,4) VALID -> (64,)  +  fc-weight staging =================
    {
        float* const sfc = sh2p;               // h2p is dead now
        if (t < 192) sfc[t] = fcwg[l * 192 + t];
        else if (t < 195) sfc[t] = fcbg[l * 3 + (t - 192)];

        const int oc4 = t >> 2, part = t & 3;
        const float* w4p = w4g + (size_t)l * 16384 + oc4 * 256 + part * 64;
        float s4 = 0.f;
        static_for<8>([&](auto J) AIL {
            constexpr int j = J.value;
            const float4 wa = ld4(w4p + j * 8);
            const float4 wb = ld4(w4p + j * 8 + 4);
            const float* xx = sA + (part * 8 + j) * 8;     // sh3[ic][kh][kw]
            const float4 xA = ld4(xx), xB = ld4(xx + 4);
            s4 = fmaf(wa.x, xA.x, s4); s4 = fmaf(wa.y, xA.y, s4);
            s4 = fmaf(wa.z, xA.z, s4); s4 = fmaf(wa.w, xA.w, s4);
            s4 = fmaf(wb.x, xB.x, s4); s4 = fmaf(wb.y, xB.y, s4);
            s4 = fmaf(wb.z, xB.z, s4); s4 = fmaf(wb.w, xB.w, s4);
        });
        sA[256 + part * 64 + oc4] = s4;                    // spart
    }
    __syncthreads();
    if (t < 64)
        sA[512 + t] = sA[256 + t] + sA[320 + t] + sA[384 + t] + sA[448 + t]
                    + b4g[l * 64 + t];                     // shf
    __syncthreads();

    // ===== FC (3x64) + softmax ====================================================
    if (t < 3) {
        const float* sfc = sh2p;
        float s = sfc[192 + t];
        static_for<64>([&](auto I) AIL { s = fmaf(sfc[t * 64 + I.value], sA[512 + I.value], s); });
        sA[576 + t] = s;                                   // slog
    }
    __syncthreads();
    if (t == 0) {
        const float a0 = sA[576], a1 = sA[577], a2 = sA[578];
        const float m = fmaxf(a0, fmaxf(a1, a2));
        const float e0 = expf(a0 - m), e1 = expf(a1 - m), e2 = expf(a2 - m);
        const float inv = 1.f / (e0 + e1 + e2);
        float* pr = preds + ((size_t)b * NLEADS + l) * 3;
        pr[0] = e0 * inv; pr[1] = e1 * inv; pr[2] = e2 * inv;
    }
}

// Cross-lead multiplicative fusion loss. One thread per (b, class).
__global__ void fusion_loss_kernel(const float* __restrict__ preds,
                                   float* __restrict__ out, int B)
{
    const int idx = blockIdx.x * blockDim.x + threadIdx.x;
    if (idx >= B * 3) return;
    const int b = idx / 3;
    const int c = idx - 3 * b;
    const float* p = preds + (size_t)b * (NLEADS * 3) + c;
    float S = 0.f;                         // log prod(1-pj)
    for (int j = 0; j < NLEADS; ++j) S += logf(1.f - p[j * 3]);
    const float be = 2.0f / 60.0f;
    float loss = 0.f;
    for (int j = 0; j < NLEADS; ++j) {
        const float pj = p[j * 3];
        loss += expf(be * (S - logf(1.f - pj))) * logf(pj);
    }
    out[idx] = -loss;
}

extern "C" void kernel_launch(void* const* d_in, const int* in_sizes, int n_in,
                              void* d_out, int out_size, void* d_ws, size_t ws_size,
                              hipStream_t stream)
{
    const float* x   = (const float*)d_in[0];
    const float* w1  = (const float*)d_in[1];
    const float* b1  = (const float*)d_in[2];
    const float* w2  = (const float*)d_in[3];
    const float* b2  = (const float*)d_in[4];
    const float* w3  = (const float*)d_in[5];
    const float* b3  = (const float*)d_in[6];
    const float* w4  = (const float*)d_in[7];
    const float* b4  = (const float*)d_in[8];
    const float* fcw = (const float*)d_in[9];
    const float* fcb = (const float*)d_in[10];

    const int B = in_sizes[0] / (NLEADS * 32 * 250);   // 128
    float* preds = (float*)d_ws;                        // B*61*3 floats

    dim3 grid(B, NLEADS);
    hipLaunchKernelGGL(lead_cnn_kernel, grid, dim3(256), 0, stream,
                       x, w1, b1, w2, b2, w3, b3, w4, b4, fcw, fcb, preds);

    const int total = B * 3;
    hipLaunchKernelGGL(fusion_loss_kernel, dim3((total + 255) / 256), dim3(256),
                       0, stream, preds, (float*)d_out, B);
}

// Round 4
// 559.685 us; speedup vs baseline: 1.6263x; 1.6263x over previous
//
#include <hip/hip_runtime.h>
#include <math.h>
#include <utility>

#define NLEADS 61
#define AIL __attribute__((always_inline))

// Guaranteed-unroll helper: indices are compile-time constants -> SROA to regs.
template <int... Is, typename F>
__device__ __forceinline__ void sf_(std::integer_sequence<int, Is...>, F&& f) {
    (f(std::integral_constant<int, Is>{}), ...);
}
template <int N, typename F>
__device__ __forceinline__ void static_for(F&& f) {
    sf_(std::make_integer_sequence<int, N>{}, (F&&)f);
}

__device__ __forceinline__ float4 ld4(const float* p) { return *(const float4*)p; }
__device__ __forceinline__ float2 ld2(const float* p) { return *(const float2*)p; }

template <int C> __device__ __forceinline__ float f4c(float4 v) {
    if constexpr (C == 0) return v.x;
    else if constexpr (C == 1) return v.y;
    else if constexpr (C == 2) return v.z;
    else return v.w;
}
template <int C> __device__ __forceinline__ float f6(float4 a, float2 b) {
    if constexpr (C < 4) return f4c<C>(a);
    else if constexpr (C == 4) return b.x;
    else return b.y;
}
template <int K> __device__ __forceinline__ float w12(float4 w0, float4 w1, float4 w2) {
    if constexpr (K < 4) return f4c<K>(w0);
    else if constexpr (K < 8) return f4c<K - 4>(w1);
    else return f4c<K - 8>(w2);
}

// LDS (floats): A[0..8703]  : h1p[8][16][68] (col-padded: col c at idx c+1)
//                             after conv2: sh3@0[256], spart@256[256], shf@512[64],
//                             slog@580[3], sfc@600[195]
//               H2[.. 1288]: h2p[16][4][20] (col-padded) + 8 guard
// Total 9992 floats = 39968 B -> 4 blocks/CU (16 waves).
__global__ __launch_bounds__(256, 4)
void lead_cnn_kernel(const float* __restrict__ x,
                     const float* __restrict__ w1g, const float* __restrict__ b1g,
                     const float* __restrict__ w2g, const float* __restrict__ b2g,
                     const float* __restrict__ w3g, const float* __restrict__ b3g,
                     const float* __restrict__ w4g, const float* __restrict__ b4g,
                     const float* __restrict__ fcwg, const float* __restrict__ fcbg,
                     float* __restrict__ preds)
{
    __shared__ __align__(16) float smem[9992];
    float* const A  = smem;
    float* const H2 = smem + 8704;

    const int t = threadIdx.x;
    const int b = blockIdx.x;
    const int l = blockIdx.y;

    const float* xg  = x + ((size_t)b * NLEADS + l) * 8000;
    const float* w1l = w1g + l * 96;       // wave-uniform -> s_load
    const float* b1l = b1g + l * 8;

    // ===== conv1 (8,1,3,4) s(1,2) p(1,2) + pool2 + relu, x read direct from HBM ====
    float acc1[32];   // [it*8+oc], constexpr-indexed
    static_for<4>([&](auto IT) AIL {
        constexpr int it = IT.value;
        const int item = t + it * 256;          // 1008..1023 compute garbage, never stored
        const int ph = item / 63;
        const int pw = item - ph * 63;
        const int c1 = (pw == 0) ? 0 : (4 * pw - 2);      // 8B-aligned
        const int c3 = (pw >= 62) ? 248 : (4 * pw + 2);   // 8B-aligned, clamped in-bounds
        const bool lok = (pw > 0), rok = (pw < 62);
        float xw[24];                           // [r*6+c]
        static_for<4>([&](auto R) AIL {
            constexpr int r = R.value;
            const int ih = 2 * ph - 1 + r;
            const int rr = (ih < 0) ? 0 : ((ih > 31) ? 31 : ih);
            const bool rowok = ((unsigned)ih < 32u);
            const float* xr = xg + rr * 250;
            const float2 e0 = ld2(xr + c1);
            const float2 e1 = ld2(xr + 4 * pw);
            const float2 e2 = ld2(xr + c3);
            const bool okl = rowok & lok, okr = rowok & rok;
            xw[r*6+0] = okl ? e0.x : 0.f;
            xw[r*6+1] = okl ? e0.y : 0.f;
            xw[r*6+2] = rowok ? e1.x : 0.f;
            xw[r*6+3] = rowok ? e1.y : 0.f;
            xw[r*6+4] = okr ? e2.x : 0.f;
            xw[r*6+5] = okr ? e2.y : 0.f;
        });
        static_for<8>([&](auto OC) AIL {
            constexpr int oc = OC.value;
            const float4 q0 = ld4(w1l + oc * 12);      // uniform -> SGPR
            const float4 q1 = ld4(w1l + oc * 12 + 4);
            const float4 q2 = ld4(w1l + oc * 12 + 8);
            float p00 = 0.f, p01 = 0.f, p10 = 0.f, p11 = 0.f;
            static_for<3>([&](auto KH) AIL {
                constexpr int kh = KH.value;
                static_for<4>([&](auto KW) AIL {
                    constexpr int kw = KW.value;
                    const float wv = w12<kh * 4 + kw>(q0, q1, q2);
                    p00 = fmaf(wv, xw[kh * 6 + kw], p00);
                    p01 = fmaf(wv, xw[kh * 6 + kw + 2], p01);
                    p10 = fmaf(wv, xw[(kh + 1) * 6 + kw], p10);
                    p11 = fmaf(wv, xw[(kh + 1) * 6 + kw + 2], p11);
                });
            });
            const float m = fmaxf(fmaxf(p00, p01), fmaxf(p10, p11));
            acc1[it * 8 + oc] = fmaxf(m + b1l[oc], 0.f);
        });
    });
    // store h1p interior (col c -> idx c+1) + zero col pads
    static_for<4>([&](auto IT) AIL {
        constexpr int it = IT.value;
        const int item = t + it * 256;
        if (item < 1008) {
            const int ph = item / 63;
            const int pw = item - ph * 63;
            const int base = ph * 68 + pw + 1;
            static_for<8>([&](auto OC) AIL {
                A[OC.value * 1088 + base] = acc1[it * 8 + OC.value];
            });
        }
    });
    for (int i = t; i < 640; i += 256) {          // cols 0 and 64..67, all rows/ch
        const int ch = i / 80, j = i - ch * 80;
        const int r = j / 5, k = j - r * 5;
        A[ch * 1088 + r * 68 + ((k == 0) ? 0 : (63 + k))] = 0.f;
    }
    for (int i = t; i < 128; i += 256) {          // h2p col pads 0 and 17
        const int ch = i >> 3, r = (i >> 1) & 3;
        H2[ch * 80 + r * 20 + ((i & 1) ? 17 : 0)] = 0.f;
    }
    __syncthreads();

    // ===== conv2 (16,8,4,3) s(2,2) p(1,1) + pool2 + relu -> h2p (16,4,16) ==========
    {
        const int s2 = t & 63;
        const int ogu = __builtin_amdgcn_readfirstlane(t >> 6);   // wave-uniform
        const int ph2 = s2 >> 4, pw2 = s2 & 15;
        float a2[16];
        static_for<16>([&](auto I) AIL { a2[I.value] = 0.f; });
        static_for<8>([&](auto IC) AIL {
            constexpr int ic = IC.value;
            float4 ya[6]; float2 yb[6];
            static_for<6>([&](auto R) AIL {
                constexpr int r = R.value;
                const int Rr = 4 * ph2 - 1 + r;
                const int rr = (Rr < 0) ? 0 : ((Rr > 15) ? 15 : Rr);
                const float* hp = A + ic * 1088 + rr * 68 + 4 * pw2;  // 16B-aligned
                float4 va = ld4(hp);
                float2 vb = ld2(hp + 4);
                if constexpr (r == 0 || r == 5) {     // only rows that can be OOB
                    const bool ok = ((unsigned)Rr < 16u);
                    va.x = ok ? va.x : 0.f; va.y = ok ? va.y : 0.f;
                    va.z = ok ? va.z : 0.f; va.w = ok ? va.w : 0.f;
                    vb.x = ok ? vb.x : 0.f; vb.y = ok ? vb.y : 0.f;
                }
                ya[r] = va; yb[r] = vb;
            });
            static_for<4>([&](auto OL) AIL {
                constexpr int ol = OL.value;
                const float* wp = w2g + ((size_t)((l * 16 + ogu * 4 + ol) * 8 + ic)) * 12;
                const float4 q0 = ld4(wp), q1 = ld4(wp + 4), q2 = ld4(wp + 8);  // uniform
                static_for<4>([&](auto KH) AIL {
                    constexpr int kh = KH.value;
                    static_for<3>([&](auto KW) AIL {
                        constexpr int kw = KW.value;
                        const float wv = w12<kh * 3 + kw>(q0, q1, q2);
                        a2[ol*4+0] = fmaf(wv, f6<kw>(ya[kh], yb[kh]), a2[ol*4+0]);
                        a2[ol*4+1] = fmaf(wv, f6<kw + 2>(ya[kh], yb[kh]), a2[ol*4+1]);
                        a2[ol*4+2] = fmaf(wv, f6<kw>(ya[kh + 2], yb[kh + 2]), a2[ol*4+2]);
                        a2[ol*4+3] = fmaf(wv, f6<kw + 2>(ya[kh + 2], yb[kh + 2]), a2[ol*4+3]);
                    });
                });
            });
        });
        static_for<4>([&](auto OL) AIL {
            constexpr int ol = OL.value;
            const int oc = ogu * 4 + ol;
            const float m = fmaxf(fmaxf(a2[ol*4+0], a2[ol*4+1]),
                                  fmaxf(a2[ol*4+2], a2[ol*4+3]));
            H2[oc * 80 + ph2 * 20 + pw2 + 1] = fmaxf(m + b2g[l * 16 + oc], 0.f);
        });
    }
    __syncthreads();

    // ===== conv3 (32,16,3,4) s(1,2) p(1,1) + pool2 + relu -> sh3 (32,2,4) ==========
    {
        const int oc3 = t >> 3, s3 = t & 7;
        const int ph3 = s3 >> 2, pw3 = s3 & 3;
        const float* w3l = w3g + (size_t)l * 6144 + oc3 * 192;
        const float b3v = b3g[l * 32 + oc3];
        float a30 = 0.f, a31 = 0.f, a32 = 0.f, a33 = 0.f;
        static_for<16>([&](auto IC) AIL {
            constexpr int ic = IC.value;
            float4 za[4]; float2 zb[4];
            static_for<4>([&](auto R) AIL {
                constexpr int r = R.value;
                const int Rr = 2 * ph3 - 1 + r;
                const int rr = (Rr < 0) ? 0 : ((Rr > 3) ? 3 : Rr);
                const float* zp = H2 + ic * 80 + rr * 20 + 4 * pw3;   // 16B-aligned
                float4 va = ld4(zp);
                float2 vb = ld2(zp + 4);
                if constexpr (r == 0 || r == 3) {
                    const bool ok = ((unsigned)Rr < 4u);
                    va.x = ok ? va.x : 0.f; va.y = ok ? va.y : 0.f;
                    va.z = ok ? va.z : 0.f; va.w = ok ? va.w : 0.f;
                    vb.x = ok ? vb.x : 0.f; vb.y = ok ? vb.y : 0.f;
                }
                za[r] = va; zb[r] = vb;
            });
            const float4 q0 = ld4(w3l + ic * 12);
            const float4 q1 = ld4(w3l + ic * 12 + 4);
            const float4 q2 = ld4(w3l + ic * 12 + 8);
            static_for<3>([&](auto KH) AIL {
                constexpr int kh = KH.value;
                static_for<4>([&](auto KW) AIL {
                    constexpr int kw = KW.value;
                    const float wv = w12<kh * 4 + kw>(q0, q1, q2);
                    a30 = fmaf(wv, f6<kw>(za[kh], zb[kh]), a30);
                    a31 = fmaf(wv, f6<kw + 2>(za[kh], zb[kh]), a31);
                    a32 = fmaf(wv, f6<kw>(za[kh + 1], zb[kh + 1]), a32);
                    a33 = fmaf(wv, f6<kw + 2>(za[kh + 1], zb[kh + 1]), a33);
                });
            });
        });
        const float m = fmaxf(fmaxf(a30, a31), fmaxf(a32, a33));
        A[oc3 * 8 + s3] = fmaxf(m + b3v, 0.f);    // sh3, h1p region is dead
    }
    __syncthreads();

    // ===== conv4 (64,32,2,4) VALID -> (64,) + fc-weight staging ====================
    {
        if (t < 192) A[600 + t] = fcwg[l * 192 + t];
        else if (t < 195) A[600 + t] = fcbg[l * 3 + (t - 192)];

        const int oc4 = t >> 2, part = t & 3;
        const float* w4p = w4g + (size_t)l * 16384 + oc4 * 256 + part * 64;
        float s4 = 0.f;
        static_for<8>([&](auto J) AIL {
            constexpr int j = J.value;
            const float4 wa = ld4(w4p + j * 8);
            const float4 wb = ld4(w4p + j * 8 + 4);
            const float* xx = A + (part * 8 + j) * 8;
            const float4 xA = ld4(xx), xB = ld4(xx + 4);
            s4 = fmaf(wa.x, xA.x, s4); s4 = fmaf(wa.y, xA.y, s4);
            s4 = fmaf(wa.z, xA.z, s4); s4 = fmaf(wa.w, xA.w, s4);
            s4 = fmaf(wb.x, xB.x, s4); s4 = fmaf(wb.y, xB.y, s4);
            s4 = fmaf(wb.z, xB.z, s4); s4 = fmaf(wb.w, xB.w, s4);
        });
        A[256 + part * 64 + oc4] = s4;            // spart
    }
    __syncthreads();
    if (t < 64)
        A[512 + t] = A[256 + t] + A[320 + t] + A[384 + t] + A[448 + t]
                   + b4g[l * 64 + t];             // shf
    __syncthreads();

    // ===== FC (3x64) + softmax =====================================================
    if (t < 3) {
        float s = A[792 + t];                     // fcb
        static_for<64>([&](auto I) AIL {
            s = fmaf(A[600 + t * 64 + I.value], A[512 + I.value], s);
        });
        A[580 + t] = s;                           // slog
    }
    __syncthreads();
    if (t == 0) {
        const float a0 = A[580], a1 = A[581], a2 = A[582];
        const float m = fmaxf(a0, fmaxf(a1, a2));
        const float e0 = expf(a0 - m), e1 = expf(a1 - m), e2 = expf(a2 - m);
        const float inv = 1.f / (e0 + e1 + e2);
        float* pr = preds + ((size_t)b * NLEADS + l) * 3;
        pr[0] = e0 * inv; pr[1] = e1 * inv; pr[2] = e2 * inv;
    }
}

// Cross-lead multiplicative fusion loss. One thread per (b, class).
__global__ void fusion_loss_kernel(const float* __restrict__ preds,
                                   float* __restrict__ out, int B)
{
    const int idx = blockIdx.x * blockDim.x + threadIdx.x;
    if (idx >= B * 3) return;
    const int b = idx / 3;
    const int c = idx - 3 * b;
    const float* p = preds + (size_t)b * (NLEADS * 3) + c;
    float S = 0.f;                                // log prod(1-pj)
    for (int j = 0; j < NLEADS; ++j) S += logf(1.f - p[j * 3]);
    const float be = 2.0f / 60.0f;
    float loss = 0.f;
    for (int j = 0; j < NLEADS; ++j) {
        const float pj = p[j * 3];
        loss += expf(be * (S - logf(1.f - pj))) * logf(pj);
    }
    out[idx] = -loss;
}

extern "C" void kernel_launch(void* const* d_in, const int* in_sizes, int n_in,
                              void* d_out, int out_size, void* d_ws, size_t ws_size,
                              hipStream_t stream)
{
    const float* x   = (const float*)d_in[0];
    const float* w1  = (const float*)d_in[1];
    const float* b1  = (const float*)d_in[2];
    const float* w2  = (const float*)d_in[3];
    const float* b2  = (const float*)d_in[4];
    const float* w3  = (const float*)d_in[5];
    const float* b3  = (const float*)d_in[6];
    const float* w4  = (const float*)d_in[7];
    const float* b4  = (const float*)d_in[8];
    const float* fcw = (const float*)d_in[9];
    const float* fcb = (const float*)d_in[10];

    const int B = in_sizes[0] / (NLEADS * 32 * 250);   // 128
    float* preds = (float*)d_ws;                        // B*61*3 floats

    dim3 grid(B, NLEADS);
    hipLaunchKernelGGL(lead_cnn_kernel, grid, dim3(256), 0, stream,
                       x, w1, b1, w2, b2, w3, b3, w4, b4, fcw, fcb, preds);

    const int total = B * 3;
    hipLaunchKernelGGL(fusion_loss_kernel, dim3((total + 255) / 256), dim3(256),
                       0, stream, preds, (float*)d_out, B);
}